// Round 1
// baseline (499.517 us; speedup 1.0000x reference)
//
#include <hip/hip_runtime.h>
#include <math.h>

#define NPTS   32768
#define NK     4
#define GRID   16
#define CIN    64
#define COUT   64
#define NCELLS (NK*GRID*GRID*GRID)   /* 16384 */
#define NENT   (NPTS*8)              /* 262144 */

// ---------------------------------------------------------------------------
// Pass 1: histogram of point-corner references per cell
// ---------------------------------------------------------------------------
__global__ void k_hist(const int* __restrict__ pidx, const float* __restrict__ pos,
                       int* __restrict__ hist, int n) {
    int p = blockIdx.x * blockDim.x + threadIdx.x;
    if (p >= n) return;
    int pk = pidx[p];
    float lx = pos[3*p+0]*16.f - 0.5f;
    float ly = pos[3*p+1]*16.f - 0.5f;
    float lz = pos[3*p+2]*16.f - 0.5f;
    int fx = (int)floorf(lx), fy = (int)floorf(ly), fz = (int)floorf(lz);
#pragma unroll
    for (int c = 0; c < 8; ++c) {
        int c0 = c & 1, c1 = (c >> 1) & 1, c2 = (c >> 2) & 1;
        int ix = min(max(fx + c0, 0), GRID-1);
        int iy = min(max(fy + c1, 0), GRID-1);
        int iz = min(max(fz + c2, 0), GRID-1);
        int cell = ((pk*GRID + iz)*GRID + iy)*GRID + ix;
        atomicAdd(&hist[cell], 1);
    }
}

// ---------------------------------------------------------------------------
// Pass 2: exclusive scan over 16384 counts (single block, 256 thr x 64 chunk)
// ---------------------------------------------------------------------------
__global__ void k_scan(const int* __restrict__ hist, int* __restrict__ offsets,
                       int* __restrict__ cursor) {
    __shared__ int sums[256];
    int t = threadIdx.x;
    int base = t * 64;
    int s = 0;
    for (int k = 0; k < 64; ++k) s += hist[base + k];
    sums[t] = s;
    __syncthreads();
    for (int off = 1; off < 256; off <<= 1) {
        int v = (t >= off) ? sums[t - off] : 0;
        __syncthreads();
        sums[t] += v;
        __syncthreads();
    }
    int p = (t == 0) ? 0 : sums[t - 1];   // exclusive prefix of this chunk
    for (int k = 0; k < 64; ++k) {
        int i = base + k;
        int h = hist[i];
        offsets[i] = p;
        cursor[i]  = p;
        p += h;
    }
}

// ---------------------------------------------------------------------------
// Pass 3: scatter (point_id, weight) entries into per-cell CSR buckets
// ---------------------------------------------------------------------------
__global__ void k_scatter(const int* __restrict__ pidx, const float* __restrict__ pos,
                          int* __restrict__ cursor, int* __restrict__ epid,
                          float* __restrict__ ew, int n) {
    int p = blockIdx.x * blockDim.x + threadIdx.x;
    if (p >= n) return;
    int pk = pidx[p];
    float lx = pos[3*p+0]*16.f - 0.5f;
    float ly = pos[3*p+1]*16.f - 0.5f;
    float lz = pos[3*p+2]*16.f - 0.5f;
    float flx = floorf(lx), fly = floorf(ly), flz = floorf(lz);
    int fx = (int)flx, fy = (int)fly, fz = (int)flz;
    float tx = lx - flx, ty = ly - fly, tz = lz - flz;
    float wx[2] = {1.f - tx, tx};
    float wy[2] = {1.f - ty, ty};
    float wz[2] = {1.f - tz, tz};
#pragma unroll
    for (int c = 0; c < 8; ++c) {
        int c0 = c & 1, c1 = (c >> 1) & 1, c2 = (c >> 2) & 1;
        int ix = min(max(fx + c0, 0), GRID-1);
        int iy = min(max(fy + c1, 0), GRID-1);
        int iz = min(max(fz + c2, 0), GRID-1);
        int cell = ((pk*GRID + iz)*GRID + iy)*GRID + ix;
        float w = wx[c0] * wy[c1] * wz[c2];
        int e = atomicAdd(&cursor[cell], 1);
        epid[e] = p;
        ew[e]   = w;
    }
}

// ---------------------------------------------------------------------------
// Pass 4: one workgroup per cell. Stage 16 KB K-block in LDS, then one wave
// per entry: dot(x_row, K[:,f]) for 64 channels, scaled atomic-add into out.
// Lane layout: l = q*16 + g ; lane reads rows r ≡ q (mod 4), channels 4g..4g+3
// via ds_read_b128. After shfl_xor(16/32) reduction, lane l owns channel
// cOut = 4g + q and issues one HW fp32 atomic.
// ---------------------------------------------------------------------------
__global__ __launch_bounds__(256)
void k_main(const float* __restrict__ xs, const float* __restrict__ kernels,
            const float* __restrict__ biases, const int* __restrict__ offsets,
            const int* __restrict__ hist, const int* __restrict__ epid,
            const float* __restrict__ ew, float* __restrict__ out) {
    __shared__ float Ks[CIN * COUT];   // 16 KB
    int cell  = blockIdx.x;
    int start = offsets[cell];
    int cnt   = hist[cell];
    if (cnt == 0) return;

    int tid = threadIdx.x;
    const float* Kg = kernels + (size_t)cell * (CIN * COUT);
    // stage K block: 1024 float4, 4 per thread, coalesced
    for (int j = tid; j < (CIN * COUT / 4); j += 256) {
        ((float4*)Ks)[j] = ((const float4*)Kg)[j];
    }

    int l  = tid & 63;          // lane
    int wv = tid >> 6;          // wave id 0..3
    int q  = l >> 4;            // row-phase 0..3
    int g  = l & 15;            // channel group
    int cOut = (g << 2) + q;    // channel this lane will write
    float bOut = biases[(size_t)cell * COUT + cOut];
    __syncthreads();

    for (int e = start + wv; e < start + cnt; e += 4) {
        int   pid = epid[e];
        float wgt = ew[e];
        float xv  = xs[(size_t)pid * CIN + l];   // lane l holds x[l]
        float a0 = 0.f, a1 = 0.f, a2 = 0.f, a3 = 0.f;
#pragma unroll
        for (int ib = 0; ib < CIN; ib += 4) {
            int r = ib + q;
            float xr = __shfl(xv, r);
            const float4 kf = *((const float4*)&Ks[r * COUT + (g << 2)]);
            a0 = fmaf(xr, kf.x, a0);
            a1 = fmaf(xr, kf.y, a1);
            a2 = fmaf(xr, kf.z, a2);
            a3 = fmaf(xr, kf.w, a3);
        }
        // reduce across the 4 row-phases (lanes l^16, l^32)
        a0 += __shfl_xor(a0, 16); a0 += __shfl_xor(a0, 32);
        a1 += __shfl_xor(a1, 16); a1 += __shfl_xor(a1, 32);
        a2 += __shfl_xor(a2, 16); a2 += __shfl_xor(a2, 32);
        a3 += __shfl_xor(a3, 16); a3 += __shfl_xor(a3, 32);
        float dot = (q == 0) ? a0 : (q == 1) ? a1 : (q == 2) ? a2 : a3;
        unsafeAtomicAdd(&out[(size_t)pid * COUT + cOut], wgt * (dot + bOut));
    }
}

// ---------------------------------------------------------------------------
extern "C" void kernel_launch(void* const* d_in, const int* in_sizes, int n_in,
                              void* d_out, int out_size, void* d_ws, size_t ws_size,
                              hipStream_t stream) {
    const int*   pidx    = (const int*)  d_in[0];
    const float* pos     = (const float*)d_in[1];
    const float* xs      = (const float*)d_in[2];
    const float* kernels = (const float*)d_in[3];
    const float* biases  = (const float*)d_in[4];
    float*       out     = (float*)d_out;
    int n = in_sizes[0];   // 32768 (N,1)

    // workspace layout (ints): hist[16384] | offsets[16384] | cursor[16384]
    //                          epid[262144] | ew[262144]  -> ~2.3 MB total
    int* ws      = (int*)d_ws;
    int* hist    = ws;
    int* offsets = ws + NCELLS;
    int* cursor  = ws + 2 * NCELLS;
    int* epid    = ws + 3 * NCELLS;
    float* ew    = (float*)(ws + 3 * NCELLS + NENT);

    hipMemsetAsync(hist, 0, NCELLS * sizeof(int), stream);
    hipMemsetAsync(d_out, 0, (size_t)out_size * sizeof(float), stream);

    int blocks = (n + 255) / 256;
    k_hist   <<<blocks, 256, 0, stream>>>(pidx, pos, hist, n);
    k_scan   <<<1,      256, 0, stream>>>(hist, offsets, cursor);
    k_scatter<<<blocks, 256, 0, stream>>>(pidx, pos, cursor, epid, ew, n);
    k_main   <<<NCELLS, 256, 0, stream>>>(xs, kernels, biases, offsets, hist,
                                          epid, ew, out);
}

// Round 2
// 422.646 us; speedup vs baseline: 1.1819x; 1.1819x over previous
//
#include <hip/hip_runtime.h>
#include <math.h>

#define NPTS   32768
#define NK     4
#define GRID   16
#define CIN    64
#define COUT   64
#define NCELLS (NK*GRID*GRID*GRID)   /* 16384 */
#define NENT   (NPTS*8)              /* 262144 */

typedef __attribute__((ext_vector_type(8))) short  short8;
typedef __attribute__((ext_vector_type(4))) float  f32x4;

static __device__ inline unsigned short f2bf(float f) {
    unsigned int u = __builtin_bit_cast(unsigned int, f);
    unsigned int r = u + 0x7fff + ((u >> 16) & 1);   // RNE truncate to bf16
    return (unsigned short)(r >> 16);
}

// ---------------------------------------------------------------------------
// Pass 1: histogram of point-corner references per cell
// ---------------------------------------------------------------------------
__global__ void k_hist(const int* __restrict__ pidx, const float* __restrict__ pos,
                       int* __restrict__ hist, int n) {
    int p = blockIdx.x * blockDim.x + threadIdx.x;
    if (p >= n) return;
    int pk = pidx[p];
    float lx = pos[3*p+0]*16.f - 0.5f;
    float ly = pos[3*p+1]*16.f - 0.5f;
    float lz = pos[3*p+2]*16.f - 0.5f;
    int fx = (int)floorf(lx), fy = (int)floorf(ly), fz = (int)floorf(lz);
#pragma unroll
    for (int c = 0; c < 8; ++c) {
        int c0 = c & 1, c1 = (c >> 1) & 1, c2 = (c >> 2) & 1;
        int ix = min(max(fx + c0, 0), GRID-1);
        int iy = min(max(fy + c1, 0), GRID-1);
        int iz = min(max(fz + c2, 0), GRID-1);
        int cell = ((pk*GRID + iz)*GRID + iy)*GRID + ix;
        atomicAdd(&hist[cell], 1);
    }
}

// ---------------------------------------------------------------------------
// Pass 2: unordered CSR allocation. Wave-scan + one global atomic per wave.
// (Order of buckets in the entry array is irrelevant for correctness.)
// ---------------------------------------------------------------------------
__global__ void k_alloc(const int* __restrict__ hist, int* __restrict__ offsets,
                        int* __restrict__ cursor, int* __restrict__ gcnt) {
    int i = blockIdx.x * blockDim.x + threadIdx.x;   // 16384 threads
    int l = threadIdx.x & 63;
    int v = hist[i];
    int p = v;
#pragma unroll
    for (int d = 1; d < 64; d <<= 1) {
        int t = __shfl_up(p, d);
        if (l >= d) p += t;
    }
    int total = __shfl(p, 63);
    int base = 0;
    if (l == 63) base = atomicAdd(gcnt, total);
    base = __shfl(base, 63);
    int off = base + p - v;       // exclusive within wave + wave base
    offsets[i] = off;
    cursor[i]  = off;
}

// ---------------------------------------------------------------------------
// Pass 3: scatter (point_id, weight) entries into per-cell CSR buckets
// ---------------------------------------------------------------------------
__global__ void k_scatter(const int* __restrict__ pidx, const float* __restrict__ pos,
                          int* __restrict__ cursor, int* __restrict__ epid,
                          float* __restrict__ ew, int n) {
    int p = blockIdx.x * blockDim.x + threadIdx.x;
    if (p >= n) return;
    int pk = pidx[p];
    float lx = pos[3*p+0]*16.f - 0.5f;
    float ly = pos[3*p+1]*16.f - 0.5f;
    float lz = pos[3*p+2]*16.f - 0.5f;
    float flx = floorf(lx), fly = floorf(ly), flz = floorf(lz);
    int fx = (int)flx, fy = (int)fly, fz = (int)flz;
    float tx = lx - flx, ty = ly - fly, tz = lz - flz;
    float wx[2] = {1.f - tx, tx};
    float wy[2] = {1.f - ty, ty};
    float wz[2] = {1.f - tz, tz};
#pragma unroll
    for (int c = 0; c < 8; ++c) {
        int c0 = c & 1, c1 = (c >> 1) & 1, c2 = (c >> 2) & 1;
        int ix = min(max(fx + c0, 0), GRID-1);
        int iy = min(max(fy + c1, 0), GRID-1);
        int iz = min(max(fz + c2, 0), GRID-1);
        int cell = ((pk*GRID + iz)*GRID + iy)*GRID + ix;
        float w = wx[c0] * wy[c1] * wz[c2];
        int e = atomicAdd(&cursor[cell], 1);
        epid[e] = p;
        ew[e]   = w;
    }
}

// ---------------------------------------------------------------------------
// Pass 4: one block (256 thr = 4 waves) per cell. Stage K as bf16 row-major
// in LDS; wave wv owns output-channel chunk [wv*16, wv*16+16). B-fragments
// (K columns) are loop-invariant -> loaded once into VGPRs. Entries processed
// in batches of 16 rows via mfma_f32_16x16x32_bf16 (M=16 entries, N=16 cout,
// K=64 in 2 steps). Epilogue: 4 fp32 HW atomics per lane per batch.
//
// Fragment layouts (gfx950, m89/m120-verified):
//   A[m][k]: m = lane&15, k = (lane>>4)*8 + j   (8 contiguous k per lane)
//   B[k][n]: n = lane&15, k = (lane>>4)*8 + j
//   D[m][n]: n = lane&15, m = (lane>>4)*4 + reg
// ---------------------------------------------------------------------------
__global__ __launch_bounds__(256)
void k_main(const float* __restrict__ xs, const float* __restrict__ kernels,
            const float* __restrict__ biases, const int* __restrict__ offsets,
            const int* __restrict__ hist, const int* __restrict__ epid,
            const float* __restrict__ ew, float* __restrict__ out) {
    __shared__ unsigned short Ks[CIN * COUT];   // 8 KB, row-major [k][n]
    __shared__ unsigned short Xb[16 * 72];      // batch A rows, stride 72 (bank pad)
    __shared__ float wB[16];
    __shared__ int   pB[16];

    int cell  = blockIdx.x;
    int start = offsets[cell];
    int cnt   = hist[cell];
    if (cnt == 0) return;
    int end = start + cnt;

    int tid = threadIdx.x;
    int l   = tid & 63;       // lane
    int wv  = tid >> 6;       // wave 0..3 -> cout chunk
    int m16 = l & 15;         // A-row / D-col index
    int q   = l >> 4;         // k-chunk / row-quad index

    // ---- stage K (fp32 global, coalesced float4) -> bf16 LDS row-major ----
    const float* Kg = kernels + (size_t)cell * (CIN * COUT);
    {
#pragma unroll
        for (int r = 0; r < 4; ++r) {
            int j = r * 1024 + tid * 4;              // element index k*64+n
            float4 kv = *(const float4*)&Kg[j];
            ushort4 kb = { f2bf(kv.x), f2bf(kv.y), f2bf(kv.z), f2bf(kv.w) };
            *(ushort4*)&Ks[j] = kb;
        }
    }
    __syncthreads();

    // ---- load loop-invariant B-fragments (K columns for this wave's chunk) ----
    int ncol = wv * 16 + m16;                        // global cout column
    short8 Bf[2];
#pragma unroll
    for (int s = 0; s < 2; ++s) {
#pragma unroll
        for (int j = 0; j < 8; ++j) {
            Bf[s][j] = (short)Ks[(s * 32 + q * 8 + j) * COUT + ncol];
        }
    }
    float bias_c = biases[(size_t)cell * COUT + ncol];

    // ---- batches of 16 entries ----
    int nb = (cnt + 15) >> 4;
    for (int b = 0; b < nb; ++b) {
        {   // stage X rows (gathered, coalesced 16B per thread) + pid/w
            int row = tid >> 4;
            int c4  = (tid & 15) << 2;
            int e   = start + (b << 4) + row;
            int pid = (e < end) ? epid[e] : 0;       // pad rows read row 0 (finite)
            float4 xv = *(const float4*)&xs[(size_t)pid * CIN + c4];
            ushort4 xb = { f2bf(xv.x), f2bf(xv.y), f2bf(xv.z), f2bf(xv.w) };
            *(ushort4*)&Xb[row * 72 + c4] = xb;
            if (tid < 16) {
                int e2 = start + (b << 4) + tid;
                bool valid = e2 < end;
                pB[tid] = valid ? epid[e2] : 0;
                wB[tid] = valid ? ew[e2] : 0.f;
            }
        }
        __syncthreads();

        f32x4 acc = {0.f, 0.f, 0.f, 0.f};
#pragma unroll
        for (int s = 0; s < 2; ++s) {
            const short8 af = *(const short8*)&Xb[m16 * 72 + s * 32 + q * 8];
            acc = __builtin_amdgcn_mfma_f32_16x16x32_bf16(af, Bf[s], acc, 0, 0, 0);
        }

#pragma unroll
        for (int reg = 0; reg < 4; ++reg) {
            int row = q * 4 + reg;                   // D row = entry index
            float w = wB[row];
            if (w != 0.f) {
                int pid = pB[row];
                float val = w * (acc[reg] + bias_c);
                unsafeAtomicAdd(&out[(size_t)pid * COUT + ncol], val);
            }
        }
        __syncthreads();                             // before Xb overwrite
    }
}

// ---------------------------------------------------------------------------
extern "C" void kernel_launch(void* const* d_in, const int* in_sizes, int n_in,
                              void* d_out, int out_size, void* d_ws, size_t ws_size,
                              hipStream_t stream) {
    const int*   pidx    = (const int*)  d_in[0];
    const float* pos     = (const float*)d_in[1];
    const float* xs      = (const float*)d_in[2];
    const float* kernels = (const float*)d_in[3];
    const float* biases  = (const float*)d_in[4];
    float*       out     = (float*)d_out;
    int n = in_sizes[0];   // 32768

    // ws ints: hist[16384] | gcnt[1] (+pad) | offsets[16384] | cursor[16384]
    //          | epid[262144] | ew[262144]
    int* ws      = (int*)d_ws;
    int* hist    = ws;
    int* gcnt    = ws + NCELLS;
    int* offsets = ws + NCELLS + 16;
    int* cursor  = offsets + NCELLS;
    int* epid    = cursor + NCELLS;
    float* ew    = (float*)(epid + NENT);

    hipMemsetAsync(hist, 0, (NCELLS + 16) * sizeof(int), stream);
    hipMemsetAsync(d_out, 0, (size_t)out_size * sizeof(float), stream);

    int blocks = (n + 255) / 256;
    k_hist   <<<blocks,       256, 0, stream>>>(pidx, pos, hist, n);
    k_alloc  <<<NCELLS / 256, 256, 0, stream>>>(hist, offsets, cursor, gcnt);
    k_scatter<<<blocks,       256, 0, stream>>>(pidx, pos, cursor, epid, ew, n);
    k_main   <<<NCELLS,       256, 0, stream>>>(xs, kernels, biases, offsets,
                                                hist, epid, ew, out);
}